// Round 7
// baseline (377.887 us; speedup 1.0000x reference)
//
#include <hip/hip_runtime.h>

#define EMB 128

typedef __attribute__((ext_vector_type(8))) short short8;
typedef __attribute__((ext_vector_type(4))) short short4v;
typedef __attribute__((ext_vector_type(4))) float floatx4;

#define MFMA(a, b, c) __builtin_amdgcn_mfma_f32_16x16x32_bf16((a), (b), (c), 0, 0, 0)

__device__ __forceinline__ ushort f2b(float f) {
    unsigned u = __float_as_uint(f);
    return (ushort)((u + 0x7fff + ((u >> 16) & 1)) >> 16);   // RNE
}
__device__ __forceinline__ float b2f(ushort h) {
    return __uint_as_float(((unsigned)h) << 16);
}
__device__ __forceinline__ short8 cvt8(const float* p) {
    float4 f0 = *(const float4*)p;
    float4 f1 = *(const float4*)(p + 4);
    short8 v;
    v[0] = f2b(f0.x); v[1] = f2b(f0.y); v[2] = f2b(f0.z); v[3] = f2b(f0.w);
    v[4] = f2b(f1.x); v[5] = f2b(f1.y); v[6] = f2b(f1.z); v[7] = f2b(f1.w);
    return v;
}

// ---------------------------------------------------------------------------
// LDS weight staging with XOR swizzle (proven round 4).  byte ^= ((row&7)<<4)
// spreads row-strided 16B fragment reads across 8 bank slots.
template <int RSH>
__device__ __forceinline__ void stage32k(const ushort* __restrict__ g,
                                         ushort* __restrict__ lds, int t) {
#pragma unroll
    for (int i = 0; i < 8; i++) {
        int a = i * 4096 + t * 16;                       // linear byte offset
        short8 v = *(const short8*)(g + (a >> 1));
        int d = a ^ (((a >> RSH) & 7) << 4);
        *(short8*)((char*)lds + d) = v;
    }
}
__device__ __forceinline__ short8 ldsW8(const ushort* lds, int byte) {   // 256B rows
    return *(const short8*)((const char*)lds + (byte ^ (((byte >> 8) & 7) << 4)));
}
__device__ __forceinline__ short8 ldsW9(const ushort* lds, int byte) {   // 512B rows
    return *(const short8*)((const char*)lds + (byte ^ (((byte >> 9) & 7) << 4)));
}

// ---------------------------------------------------------------------------
// fused independent pre-work: blocks [0,384) convert the 5 weight matrices to
// bf16; blocks [384, 384+eb) histogram right indices.
__global__ __launch_bounds__(256) void k_cvthist(const float* __restrict__ w0,
                                                 const float* __restrict__ w1,
                                                 const float* __restrict__ w2,
                                                 const float* __restrict__ w3,
                                                 const float* __restrict__ w4,
                                                 ushort* __restrict__ dst,
                                                 const int* __restrict__ eidx,
                                                 int* __restrict__ cnt,
                                                 int n_edges) {
    int bid = blockIdx.x;
    if (bid < 384) {
        int i = bid * 256 + threadIdx.x;     // 0..98303
        const float* src; int off;
        if (i < 16384)      { src = w0; off = i; }
        else if (i < 32768) { src = w1; off = i - 16384; }
        else if (i < 49152) { src = w2; off = i - 32768; }
        else if (i < 81920) { src = w3; off = i - 49152; }
        else                { src = w4; off = i - 81920; }
        dst[i] = f2b(src[off]);
    } else {
        int e = (bid - 384) * 256 + threadIdx.x;
        if (e < n_edges) atomicAdd(&cnt[eidx[n_edges + e]], 1);
    }
}

#define SCAN_CHUNK 4096
__global__ __launch_bounds__(1024) void k_scan1(const int* __restrict__ cnt,
                                                int* __restrict__ offs,
                                                int* __restrict__ bsum, int n) {
    __shared__ int buf[1024];
    int t = threadIdx.x;
    int i0 = blockIdx.x * SCAN_CHUNK + t * 4;
    int v[4];
#pragma unroll
    for (int u = 0; u < 4; u++) { int i = i0 + u; v[u] = (i < n) ? cnt[i] : 0; }
    int s = v[0] + v[1] + v[2] + v[3];
    buf[t] = s;
    __syncthreads();
    for (int d = 1; d < 1024; d <<= 1) {
        int x = (t >= d) ? buf[t - d] : 0;
        __syncthreads();
        buf[t] += x;
        __syncthreads();
    }
    int excl = buf[t] - s;
#pragma unroll
    for (int u = 0; u < 4; u++) { int i = i0 + u; if (i < n) offs[i] = excl; excl += v[u]; }
    if (t == 1023) bsum[blockIdx.x] = buf[1023];
}

__global__ __launch_bounds__(1024) void k_scan2(const int* __restrict__ bsum,
                                                int* __restrict__ offs,
                                                int* __restrict__ cursor, int n) {
    int bid = blockIdx.x;
    int base = 0;
    for (int j = 0; j < bid; j++) base += bsum[j];
    int i0 = bid * SCAN_CHUNK + threadIdx.x * 4;
#pragma unroll
    for (int u = 0; u < 4; u++) {
        int i = i0 + u;
        if (i < n) { int o = offs[i] + base; offs[i] = o; cursor[i] = o; }
    }
}

// ---------------------------------------------------------------------------
// fused scatter + projections.  SCATTER FIRST (r5's winning order): blocks
// [0, ebs) scatter 1024 edges each (4/thread -> 4 independent atomic chains);
// they retire fast and proj blocks fill in underneath.  Then left proj
// [ebs, ebs+nblk) and right proj [ebs+nblk, ebs+2nblk): 256 rows/block =
// 4 waves x 64 rows (4 row-groups of 16).  Each wave issues 32x16B
// independent X loads up front (512B in flight -> Little's law: ~8KB/CU at
// 16 waves/CU, vs 384B before -> the ~1.9 TB/s ceiling these kernels kept
// hitting).  Each LDS weight fragment is reused 4x.  launch_bounds(256,4)
// caps VGPR at 128 to hold 16 waves/CU.
__global__ __launch_bounds__(256, 4) void k_permproj(const int* __restrict__ eidx,
                                                     const float* __restrict__ ef,
                                                     int* __restrict__ cursor,
                                                     int2* __restrict__ sle,
                                                     int n_edges,
                                                     const float* __restrict__ XL,
                                                     const float* __restrict__ XR,
                                                     const ushort* __restrict__ WLb,
                                                     const ushort* __restrict__ WRb,
                                                     const float* __restrict__ bias,
                                                     ushort* __restrict__ YL,
                                                     ushort* __restrict__ YR,
                                                     int n, int ebs, int nblk) {
    __shared__ ushort Wlds[16384];
    int bid = blockIdx.x;
    int t = threadIdx.x;

    if (bid < ebs) {
        // ---- edge scatter: 4 edges/thread, independent chains ----
        int e0 = bid * 1024 + t;
        int ee[4]; int rr[4]; int ll[4]; float ff[4]; bool vv[4];
#pragma unroll
        for (int k = 0; k < 4; k++) {
            int e = e0 + k * 256;
            ee[k] = e;
            vv[k] = e < n_edges;
            rr[k] = vv[k] ? eidx[n_edges + e] : 0;
            ll[k] = vv[k] ? eidx[e] : 0;
            ff[k] = vv[k] ? ef[e] : 0.f;
        }
#pragma unroll
        for (int k = 0; k < 4; k++) {
            if (vv[k]) {
                int p = atomicAdd(&cursor[rr[k]], 1);
                int2 v; v.x = ll[k]; v.y = __float_as_int(ff[k]);
                sle[p] = v;
            }
        }
        return;
    }
    bid -= ebs;

    // ---- projection: one 256-row tile, 4 waves x 64 rows ----
    const float* X; const ushort* Wb; ushort* Y; int has_bias;
    if (bid < nblk) { X = XL; Wb = WLb; Y = YL; has_bias = 1; }
    else            { X = XR; Wb = WRb; Y = YR; has_bias = 0; bid -= nblk; }

    int wave = t >> 6, lane = t & 63;
    int m = lane & 15, quad = lane >> 4;

    stage32k<8>(Wb, Wlds, t);

    size_t base = (size_t)bid * 256 + wave * 64;
    short8 xf[4][4];
#pragma unroll
    for (int g = 0; g < 4; g++) {
        size_t r = base + g * 16 + m;
        const float* p = X + ((r < (size_t)n) ? r : (size_t)(n - 1)) * EMB;
#pragma unroll
        for (int ks = 0; ks < 4; ks++)
            xf[g][ks] = cvt8(p + ks * 32 + quad * 8);
    }
    __syncthreads();                      // weights staged

#pragma unroll
    for (int wt = 0; wt < 8; wt++) {
        short8 wv[4];
#pragma unroll
        for (int ks = 0; ks < 4; ks++)
            wv[ks] = ldsW8(Wlds, ((wt * 16 + m) << 8) + (ks << 6) + (quad << 4));
        float4 bb = {0.f, 0.f, 0.f, 0.f};
        if (has_bias) bb = *(const float4*)(bias + wt * 16 + quad * 4);
#pragma unroll
        for (int g = 0; g < 4; g++) {
            floatx4 acc = {0.f, 0.f, 0.f, 0.f};
#pragma unroll
            for (int ks = 0; ks < 4; ks++)
                acc = MFMA(wv[ks], xf[g][ks], acc);
            size_t r = base + g * 16 + m;
            if (r < (size_t)n) {
                short4v o;
                o[0] = f2b(acc[0] + bb.x);
                o[1] = f2b(acc[1] + bb.y);
                o[2] = f2b(acc[2] + bb.z);
                o[3] = f2b(acc[3] + bb.w);
                *(short4v*)(Y + r * EMB + wt * 16 + quad * 4) = o;
            }
        }
    }
}

// ---------------------------------------------------------------------------
// segmented reduction: unchanged (one wave per right node, 4 edge-groups x
// 16 lanes x 8 cols, 8 gathers in flight).
__global__ __launch_bounds__(256) void k_reduce(const ushort* __restrict__ Pl,
                                                const ushort* __restrict__ Pr,
                                                const int2* __restrict__ sle,
                                                const float* __restrict__ We,
                                                const int* __restrict__ offs,
                                                const float* __restrict__ scale_final,
                                                ushort* __restrict__ S,
                                                int n_right, int n_edges) {
    int r = blockIdx.x * 4 + (threadIdx.x >> 6);
    if (r >= n_right) return;
    int lane = threadIdx.x & 63;
    int g = lane >> 4;          // edge group 0..3
    int m = lane & 15;          // column group: cols [m*8, m*8+8)
    float scale = scale_final[0];

    float4 w0 = *(const float4*)(We + m * 8);
    float4 w1 = *(const float4*)(We + m * 8 + 4);
    short8 prv = *(const short8*)(Pr + (size_t)r * EMB + m * 8);
    float we[8], pr[8];
    we[0] = w0.x; we[1] = w0.y; we[2] = w0.z; we[3] = w0.w;
    we[4] = w1.x; we[5] = w1.y; we[6] = w1.z; we[7] = w1.w;
#pragma unroll
    for (int j = 0; j < 8; j++) pr[j] = b2f((ushort)prv[j]);

    float acc[8] = {0.f, 0.f, 0.f, 0.f, 0.f, 0.f, 0.f, 0.f};
    int s0 = offs[r];
    int s1 = (r + 1 < n_right) ? offs[r + 1] : n_edges;
    int e = s0 + g;
    for (; e + 4 < s1; e += 8) {       // two edges per group in flight
        int2 ea = sle[e];
        int2 eb = sle[e + 4];
        short8 pa = *(const short8*)(Pl + (size_t)ea.x * EMB + m * 8);
        short8 pb = *(const short8*)(Pl + (size_t)eb.x * EMB + m * 8);
        float fa = __int_as_float(ea.y), fb = __int_as_float(eb.y);
#pragma unroll
        for (int j = 0; j < 8; j++) {
            acc[j] += fmaxf((b2f((ushort)pa[j]) + pr[j] + fa * we[j]) * scale, 0.f);
            acc[j] += fmaxf((b2f((ushort)pb[j]) + pr[j] + fb * we[j]) * scale, 0.f);
        }
    }
    if (e < s1) {                      // at most one leftover per group
        int2 ea = sle[e];
        short8 pa = *(const short8*)(Pl + (size_t)ea.x * EMB + m * 8);
        float fa = __int_as_float(ea.y);
#pragma unroll
        for (int j = 0; j < 8; j++)
            acc[j] += fmaxf((b2f((ushort)pa[j]) + pr[j] + fa * we[j]) * scale, 0.f);
    }
#pragma unroll
    for (int j = 0; j < 8; j++) {
        acc[j] += __shfl_xor(acc[j], 16);
        acc[j] += __shfl_xor(acc[j], 32);
    }
    if (g == 0) {
        short8 o;
#pragma unroll
        for (int j = 0; j < 8; j++) o[j] = f2b(acc[j]);
        *(short8*)(S + (size_t)r * EMB + m * 8) = o;
    }
}

// ---------------------------------------------------------------------------
// conv GEMM + output MLP with LDS-staged weights (unchanged from round 4).
__global__ __launch_bounds__(256) void k_out(const ushort* __restrict__ S,
                                             const float* __restrict__ right,
                                             const ushort* __restrict__ Wfb,
                                             const float* __restrict__ bf,
                                             const int* __restrict__ deg,
                                             const float* __restrict__ sc_post,
                                             const ushort* __restrict__ W1b,
                                             const float* __restrict__ b1,
                                             const ushort* __restrict__ W2b,
                                             const float* __restrict__ b2,
                                             float* __restrict__ out, int n) {
    __shared__ ushort Wlds[16384];       // 32KB staging buffer
    __shared__ ushort H[64][136];
    __shared__ float degs[64];
    int t = threadIdx.x, wave = t >> 6, lane = t & 63;
    int m = lane & 15, quad = lane >> 4;
    size_t row0 = (size_t)blockIdx.x * 64;
    int rl = wave * 16 + m;
    size_t xrow = row0 + rl;
    size_t xrowc = (xrow < (size_t)n) ? xrow : (size_t)(n - 1);
    bool ok = (xrow < (size_t)n);
    float sp = sc_post[0];

    // prologue: issue all per-wave global loads early
    short8 s4[4], ar[4];
    const ushort* sr = S + xrowc * EMB;
    const float* rr = right + xrowc * EMB;
#pragma unroll
    for (int ks = 0; ks < 4; ks++)
        s4[ks] = *(const short8*)(sr + ks * 32 + quad * 8);
    stage32k<8>(Wfb, Wlds, t);
#pragma unroll
    for (int ks = 0; ks < 4; ks++)
        ar[ks] = cvt8(rr + ks * 32 + quad * 8);
    if (t < 64) {
        size_t rr2 = row0 + t;
        degs[t] = (rr2 < (size_t)n) ? (float)deg[rr2] : 0.f;
    }
    __syncthreads();                      // Wf + degs ready
    float dd = degs[rl];

    // ---- phase 1: conv = (S @ Wf^T + deg*bf) * sp -> H ----
#pragma unroll
    for (int wt = 0; wt < 8; wt++) {
        floatx4 acc = {0.f, 0.f, 0.f, 0.f};
#pragma unroll
        for (int ks = 0; ks < 4; ks++) {
            short8 w = ldsW8(Wlds, ((wt * 16 + m) << 8) + (ks << 6) + (quad << 4));
            acc = MFMA(w, s4[ks], acc);
        }
        float4 bb = *(const float4*)(bf + wt * 16 + quad * 4);
        short4v o;
        o[0] = f2b((acc[0] + dd * bb.x) * sp);
        o[1] = f2b((acc[1] + dd * bb.y) * sp);
        o[2] = f2b((acc[2] + dd * bb.z) * sp);
        o[3] = f2b((acc[3] + dd * bb.w) * sp);
        *(short4v*)(&H[rl][wt * 16 + quad * 4]) = o;
    }
    // conv B-frags (wave-local H rows; lgkmcnt orders within the wave)
    short8 c4[4];
#pragma unroll
    for (int ks = 0; ks < 4; ks++)
        c4[ks] = *(const short8*)(&H[rl][ks * 32 + quad * 8]);
    __syncthreads();                      // all waves done reading Wf
    stage32k<9>(W1b, Wlds, t);            // W1 rows 0..63 (out cols 0..63)
    __syncthreads();

    // ---- phase 2a: hidden cols 0..63 ----
#pragma unroll
    for (int wt = 0; wt < 4; wt++) {
        floatx4 acc = {0.f, 0.f, 0.f, 0.f};
        int rb = wt * 16 + m;             // buffer-local W1 row
#pragma unroll
        for (int ks = 0; ks < 4; ks++) {
            short8 w = ldsW9(Wlds, (rb << 9) + (ks << 6) + (quad << 4));
            acc = MFMA(w, c4[ks], acc);
        }
#pragma unroll
        for (int ks = 0; ks < 4; ks++) {
            short8 w = ldsW9(Wlds, (rb << 9) + 256 + (ks << 6) + (quad << 4));
            acc = MFMA(w, ar[ks], acc);
        }
        float4 bb = *(const float4*)(b1 + wt * 16 + quad * 4);
        short4v o;
        o[0] = f2b(fmaxf(acc[0] + bb.x, 0.f));
        o[1] = f2b(fmaxf(acc[1] + bb.y, 0.f));
        o[2] = f2b(fmaxf(acc[2] + bb.z, 0.f));
        o[3] = f2b(fmaxf(acc[3] + bb.w, 0.f));
        *(short4v*)(&H[rl][wt * 16 + quad * 4]) = o;
    }
    __syncthreads();                      // done reading W1a
    stage32k<9>(W1b + 16384, Wlds, t);    // W1 rows 64..127
    __syncthreads();

    // ---- phase 2b: hidden cols 64..127 ----
#pragma unroll
    for (int wt = 4; wt < 8; wt++) {
        floatx4 acc = {0.f, 0.f, 0.f, 0.f};
        int rb = (wt - 4) * 16 + m;
#pragma unroll
        for (int ks = 0; ks < 4; ks++) {
            short8 w = ldsW9(Wlds, (rb << 9) + (ks << 6) + (quad << 4));
            acc = MFMA(w, c4[ks], acc);
        }
#pragma unroll
        for (int ks = 0; ks < 4; ks++) {
            short8 w = ldsW9(Wlds, (rb << 9) + 256 + (ks << 6) + (quad << 4));
            acc = MFMA(w, ar[ks], acc);
        }
        float4 bb = *(const float4*)(b1 + wt * 16 + quad * 4);
        short4v o;
        o[0] = f2b(fmaxf(acc[0] + bb.x, 0.f));
        o[1] = f2b(fmaxf(acc[1] + bb.y, 0.f));
        o[2] = f2b(fmaxf(acc[2] + bb.z, 0.f));
        o[3] = f2b(fmaxf(acc[3] + bb.w, 0.f));
        *(short4v*)(&H[rl][wt * 16 + quad * 4]) = o;
    }
    short8 h4[4];
#pragma unroll
    for (int ks = 0; ks < 4; ks++)
        h4[ks] = *(const short8*)(&H[rl][ks * 32 + quad * 8]);
    __syncthreads();                      // done reading W1b
    stage32k<8>(W2b, Wlds, t);
    __syncthreads();

    // ---- phase 3: out = hidden @ W2^T + b2 (coalesced float4 stores) ----
#pragma unroll
    for (int wt = 0; wt < 8; wt++) {
        floatx4 acc = {0.f, 0.f, 0.f, 0.f};
#pragma unroll
        for (int ks = 0; ks < 4; ks++) {
            short8 w = ldsW8(Wlds, ((wt * 16 + m) << 8) + (ks << 6) + (quad << 4));
            acc = MFMA(w, h4[ks], acc);
        }
        if (ok) {
            float4 bb = *(const float4*)(b2 + wt * 16 + quad * 4);
            float4 o;
            o.x = acc[0] + bb.x;
            o.y = acc[1] + bb.y;
            o.z = acc[2] + bb.z;
            o.w = acc[3] + bb.w;
            *(float4*)(out + xrow * EMB + wt * 16 + quad * 4) = o;
        }
    }
}

// ---------------------------------------------------------------------------
extern "C" void kernel_launch(void* const* d_in, const int* in_sizes, int n_in,
                              void* d_out, int out_size, void* d_ws, size_t ws_size,
                              hipStream_t stream) {
    const float* left   = (const float*)d_in[0];
    const int*   eidx   = (const int*)  d_in[1];
    const float* efeat  = (const float*)d_in[2];
    const float* right  = (const float*)d_in[3];
    const float* W_left = (const float*)d_in[5];
    const float* b_left = (const float*)d_in[6];
    const float* W_edge = (const float*)d_in[7];
    const float* W_right= (const float*)d_in[8];
    const float* sc_fin = (const float*)d_in[9];
    const float* W_fin  = (const float*)d_in[10];
    const float* b_fin  = (const float*)d_in[11];
    const float* sc_post= (const float*)d_in[12];
    const float* W_out1 = (const float*)d_in[13];
    const float* b_out1 = (const float*)d_in[14];
    const float* W_out2 = (const float*)d_in[15];
    const float* b_out2 = (const float*)d_in[16];

    int n_left  = in_sizes[0] / EMB;        // 100000
    int n_edges = in_sizes[2];              // 600000
    int n_right = in_sizes[3] / EMB;        // 100000

    ushort* us = (ushort*)d_ws;
    ushort* Wl_b = us;                       // packed bf16 weights
    ushort* Wr_b = us + 16384;
    ushort* Wf_b = us + 32768;
    ushort* W1_b = us + 49152;
    ushort* W2_b = us + 81920;
    ushort* Pl   = us + 98304;               // n_left*128
    ushort* Pr   = Pl + (size_t)n_left * EMB;
    ushort* S    = Pr + (size_t)n_right * EMB;
    int* cnt    = (int*)(S + (size_t)n_right * EMB);
    int* offs   = cnt + n_right;
    int* cursor = offs + n_right;
    int* bsum   = cursor + n_right;
    int2* sle   = (int2*)(bsum + 64);

    hipMemsetAsync(cnt, 0, (size_t)n_right * sizeof(int), stream);

    int ebh = (n_edges + 255) / 256;         // 2344 (histogram)
    int ebs = (n_edges + 1023) / 1024;       // 586 (scatter, 4 edges/thread)
    int nblk = (n_left + 255) / 256;         // 391 (proj tiles per side)
    int nsb = (n_right + SCAN_CHUNK - 1) / SCAN_CHUNK;   // 25

    // weights->bf16 + degree histogram (independent, one launch)
    k_cvthist<<<384 + ebh, 256, 0, stream>>>(W_left, W_right, W_fin, W_out1,
                                             W_out2, us, eidx, cnt, n_edges);

    // exclusive scan of degrees
    k_scan1<<<nsb, 1024, 0, stream>>>(cnt, offs, bsum, n_right);
    k_scan2<<<nsb, 1024, 0, stream>>>(bsum, offs, cursor, n_right);

    // edge scatter (blocks first, retire fast) + projections underneath
    k_permproj<<<ebs + 2 * nblk, 256, 0, stream>>>(eidx, efeat, cursor, sle,
                                                   n_edges, left, right,
                                                   Wl_b, Wr_b, b_left,
                                                   Pl, Pr, n_left, ebs, nblk);

    // segmented reduction -> S (one wave per right node, 4-wide gather)
    k_reduce<<<(n_right + 3) / 4, 256, 0, stream>>>(Pl, Pr, sle, W_edge, offs,
                                                    sc_fin, S, n_right, n_edges);

    // conv GEMM + output MLP (LDS-staged weights)
    k_out<<<(n_right + 63) / 64, 256, 0, stream>>>(S, right, Wf_b, b_fin,
                                                   cnt, sc_post, W1_b, b_out1,
                                                   W2_b, b_out2,
                                                   (float*)d_out, n_right);
}

// Round 8
// 335.305 us; speedup vs baseline: 1.1270x; 1.1270x over previous
//
#include <hip/hip_runtime.h>

#define EMB 128

typedef __attribute__((ext_vector_type(8))) short short8;
typedef __attribute__((ext_vector_type(4))) short short4v;
typedef __attribute__((ext_vector_type(4))) float floatx4;

#define MFMA(a, b, c) __builtin_amdgcn_mfma_f32_16x16x32_bf16((a), (b), (c), 0, 0, 0)

__device__ __forceinline__ ushort f2b(float f) {
    unsigned u = __float_as_uint(f);
    return (ushort)((u + 0x7fff + ((u >> 16) & 1)) >> 16);   // RNE
}
__device__ __forceinline__ float b2f(ushort h) {
    return __uint_as_float(((unsigned)h) << 16);
}
__device__ __forceinline__ short8 cvt8(const float* p) {
    float4 f0 = *(const float4*)p;
    float4 f1 = *(const float4*)(p + 4);
    short8 v;
    v[0] = f2b(f0.x); v[1] = f2b(f0.y); v[2] = f2b(f0.z); v[3] = f2b(f0.w);
    v[4] = f2b(f1.x); v[5] = f2b(f1.y); v[6] = f2b(f1.z); v[7] = f2b(f1.w);
    return v;
}

// ---------------------------------------------------------------------------
// LDS weight staging with XOR swizzle (proven round 4).
template <int RSH>
__device__ __forceinline__ void stage32k(const ushort* __restrict__ g,
                                         ushort* __restrict__ lds, int t) {
#pragma unroll
    for (int i = 0; i < 8; i++) {
        int a = i * 4096 + t * 16;                       // linear byte offset
        short8 v = *(const short8*)(g + (a >> 1));
        int d = a ^ (((a >> RSH) & 7) << 4);
        *(short8*)((char*)lds + d) = v;
    }
}
__device__ __forceinline__ short8 ldsW8(const ushort* lds, int byte) {   // 256B rows
    return *(const short8*)((const char*)lds + (byte ^ (((byte >> 8) & 7) << 4)));
}
__device__ __forceinline__ short8 ldsW9(const ushort* lds, int byte) {   // 512B rows
    return *(const short8*)((const char*)lds + (byte ^ (((byte >> 9) & 7) << 4)));
}

// ---------------------------------------------------------------------------
// async global->LDS, 16B per lane.  LDS dest = wave-uniform base + lane*16
// (linear); global source is per-lane (free to permute).
__device__ __forceinline__ void gld16(const float* gp, void* lbase) {
    __builtin_amdgcn_global_load_lds(
        (const __attribute__((address_space(1))) unsigned int*)gp,
        (__attribute__((address_space(3))) unsigned int*)lbase, 16, 0, 0);
}

// Stage one 16-row x 512B fp32 X tile into LDS, XOR-swizzled layout
// (swz(a) = a ^ (((a>>9)&7)<<4), an involution).  gload_lds writes the LDS
// linearly; the swizzle is applied by PRE-SWIZZLING the global source byte
// (rule: linear dest + inverse-swz source + swz on read).  OOB rows clamp
// to row n-1 (stores are guarded).
__device__ __forceinline__ void stageX(const float* __restrict__ X, int n,
                                       float* buf, int tile, int wave, int lane) {
    size_t R0 = (size_t)tile * 16;
    const char* base = (const char*)(X + R0 * EMB);
#pragma unroll
    for (int i = 0; i < 2; i++) {
        int abase = i * 4096 + wave * 1024;
        int a = abase + lane * 16;
        int src = a ^ (((a >> 9) & 7) << 4);
        int rl = src >> 9;                         // local row 0..15
        if (R0 + (size_t)rl >= (size_t)n) rl = (int)((size_t)(n - 1) - R0);
        const float* gp = (const float*)(base + (size_t)rl * 512 + (src & 511));
        gld16(gp, (char*)buf + abase);
    }
}
__device__ __forceinline__ float4 ldsX(const float* buf, int byte) {
    return *(const float4*)((const char*)buf + (byte ^ (((byte >> 9) & 7) << 4)));
}

// ---------------------------------------------------------------------------
// fused independent pre-work: blocks [0,384) convert the 5 weight matrices to
// bf16; blocks [384, 384+eb) histogram right indices.
__global__ __launch_bounds__(256) void k_cvthist(const float* __restrict__ w0,
                                                 const float* __restrict__ w1,
                                                 const float* __restrict__ w2,
                                                 const float* __restrict__ w3,
                                                 const float* __restrict__ w4,
                                                 ushort* __restrict__ dst,
                                                 const int* __restrict__ eidx,
                                                 int* __restrict__ cnt,
                                                 int n_edges) {
    int bid = blockIdx.x;
    if (bid < 384) {
        int i = bid * 256 + threadIdx.x;     // 0..98303
        const float* src; int off;
        if (i < 16384)      { src = w0; off = i; }
        else if (i < 32768) { src = w1; off = i - 16384; }
        else if (i < 49152) { src = w2; off = i - 32768; }
        else if (i < 81920) { src = w3; off = i - 49152; }
        else                { src = w4; off = i - 81920; }
        dst[i] = f2b(src[off]);
    } else {
        int e = (bid - 384) * 256 + threadIdx.x;
        if (e < n_edges) atomicAdd(&cnt[eidx[n_edges + e]], 1);
    }
}

#define SCAN_CHUNK 4096
__global__ __launch_bounds__(1024) void k_scan1(const int* __restrict__ cnt,
                                                int* __restrict__ offs,
                                                int* __restrict__ bsum, int n) {
    __shared__ int buf[1024];
    int t = threadIdx.x;
    int i0 = blockIdx.x * SCAN_CHUNK + t * 4;
    int v[4];
#pragma unroll
    for (int u = 0; u < 4; u++) { int i = i0 + u; v[u] = (i < n) ? cnt[i] : 0; }
    int s = v[0] + v[1] + v[2] + v[3];
    buf[t] = s;
    __syncthreads();
    for (int d = 1; d < 1024; d <<= 1) {
        int x = (t >= d) ? buf[t - d] : 0;
        __syncthreads();
        buf[t] += x;
        __syncthreads();
    }
    int excl = buf[t] - s;
#pragma unroll
    for (int u = 0; u < 4; u++) { int i = i0 + u; if (i < n) offs[i] = excl; excl += v[u]; }
    if (t == 1023) bsum[blockIdx.x] = buf[1023];
}

__global__ __launch_bounds__(1024) void k_scan2(const int* __restrict__ bsum,
                                                int* __restrict__ offs,
                                                int* __restrict__ cursor, int n) {
    int bid = blockIdx.x;
    int base = 0;
    for (int j = 0; j < bid; j++) base += bsum[j];
    int i0 = bid * SCAN_CHUNK + threadIdx.x * 4;
#pragma unroll
    for (int u = 0; u < 4; u++) {
        int i = i0 + u;
        if (i < n) { int o = offs[i] + base; offs[i] = o; cursor[i] = o; }
    }
}

// ---------------------------------------------------------------------------
// fused scatter + projections.  Scatter blocks [0, eb) first (r5's winning
// order, 1 edge/thread).  Then PB proj blocks per side, each looping over
// 16-row X tiles with a gload_lds DOUBLE-BUFFER: issue stage(t+1), compute
// tile t from LDS, __syncthreads (drains vmcnt).  In-flight bytes now live
// in the LDS-DMA queue instead of VGPRs: 3 blocks/CU x 8KB = 24KB/CU in
// flight -> BW-saturating (reg-staged versions capped at ~5KB -> 1.8TB/s).
// Weight fragments + bias hoisted to registers once per block; 4 waves
// split the 128 output columns (colbase = wave*32).
#define PB 384
__global__ __launch_bounds__(256) void k_permproj(const int* __restrict__ eidx,
                                                  const float* __restrict__ ef,
                                                  int* __restrict__ cursor,
                                                  int2* __restrict__ sle,
                                                  int n_edges,
                                                  const float* __restrict__ XL,
                                                  const float* __restrict__ XR,
                                                  const ushort* __restrict__ WLb,
                                                  const ushort* __restrict__ WRb,
                                                  const float* __restrict__ bias,
                                                  ushort* __restrict__ YL,
                                                  ushort* __restrict__ YR,
                                                  int n, int eb) {
    __shared__ ushort Wlds[16384];         // 32KB weights
    __shared__ float Xlds[2][2048];        // 2 x 8KB fp32 X tile (16 rows)
    int bid = blockIdx.x;
    int t = threadIdx.x;

    if (bid < eb) {
        int e = bid * 256 + t;
        if (e < n_edges) {
            int r = eidx[n_edges + e];
            int p = atomicAdd(&cursor[r], 1);
            int2 v; v.x = eidx[e]; v.y = __float_as_int(ef[e]);
            sle[p] = v;
        }
        return;
    }
    bid -= eb;

    const float* X; const ushort* Wb; ushort* Y; int has_bias;
    if (bid < PB) { X = XL; Wb = WLb; Y = YL; has_bias = 1; }
    else          { X = XR; Wb = WRb; Y = YR; has_bias = 0; bid -= PB; }

    int wave = t >> 6, lane = t & 63;
    int m = lane & 15, quad = lane >> 4;
    int colbase = wave * 32;
    int ntiles = (n + 15) >> 4;

    stage32k<8>(Wb, Wlds, t);
    stageX(X, n, Xlds[0], bid, wave, lane);
    __syncthreads();                        // weights + first tile staged

    // hoist weight fragments + bias (constant across tiles)
    short8 wv[2][4];
    float4 bbv[2];
#pragma unroll
    for (int ct = 0; ct < 2; ct++) {
#pragma unroll
        for (int ks = 0; ks < 4; ks++)
            wv[ct][ks] = ldsW8(Wlds, ((colbase + ct * 16 + m) << 8) + (ks << 6) + (quad << 4));
        if (has_bias) bbv[ct] = *(const float4*)(bias + colbase + ct * 16 + quad * 4);
        else { bbv[ct].x = 0.f; bbv[ct].y = 0.f; bbv[ct].z = 0.f; bbv[ct].w = 0.f; }
    }

    int cur = 0;
    for (int tile = bid; tile < ntiles; tile += PB) {
        int nxt = tile + PB;
        if (nxt < ntiles) stageX(X, n, Xlds[cur ^ 1], nxt, wave, lane);

        const float* xb = Xlds[cur];
        size_t row = (size_t)tile * 16 + m;
        bool ok = row < (size_t)n;

        short8 xf[4];
#pragma unroll
        for (int ks = 0; ks < 4; ks++) {
            int b0 = m * 512 + ks * 128 + quad * 32;
            float4 f0 = ldsX(xb, b0);
            float4 f1 = ldsX(xb, b0 + 16);
            short8 v;
            v[0] = f2b(f0.x); v[1] = f2b(f0.y); v[2] = f2b(f0.z); v[3] = f2b(f0.w);
            v[4] = f2b(f1.x); v[5] = f2b(f1.y); v[6] = f2b(f1.z); v[7] = f2b(f1.w);
            xf[ks] = v;
        }
#pragma unroll
        for (int ct = 0; ct < 2; ct++) {
            floatx4 acc = {0.f, 0.f, 0.f, 0.f};
#pragma unroll
            for (int ks = 0; ks < 4; ks++)
                acc = MFMA(wv[ct][ks], xf[ks], acc);
            if (ok) {
                short4v o;
                o[0] = f2b(acc[0] + bbv[ct].x);
                o[1] = f2b(acc[1] + bbv[ct].y);
                o[2] = f2b(acc[2] + bbv[ct].z);
                o[3] = f2b(acc[3] + bbv[ct].w);
                *(short4v*)(Y + row * EMB + colbase + ct * 16 + quad * 4) = o;
            }
        }
        __syncthreads();                    // drains vmcnt: next tile staged,
        cur ^= 1;                           // all waves done reading cur
    }
}

// ---------------------------------------------------------------------------
// segmented reduction: unchanged (one wave per right node, 4 edge-groups x
// 16 lanes x 8 cols, 8 gathers in flight).
__global__ __launch_bounds__(256) void k_reduce(const ushort* __restrict__ Pl,
                                                const ushort* __restrict__ Pr,
                                                const int2* __restrict__ sle,
                                                const float* __restrict__ We,
                                                const int* __restrict__ offs,
                                                const float* __restrict__ scale_final,
                                                ushort* __restrict__ S,
                                                int n_right, int n_edges) {
    int r = blockIdx.x * 4 + (threadIdx.x >> 6);
    if (r >= n_right) return;
    int lane = threadIdx.x & 63;
    int g = lane >> 4;          // edge group 0..3
    int m = lane & 15;          // column group: cols [m*8, m*8+8)
    float scale = scale_final[0];

    float4 w0 = *(const float4*)(We + m * 8);
    float4 w1 = *(const float4*)(We + m * 8 + 4);
    short8 prv = *(const short8*)(Pr + (size_t)r * EMB + m * 8);
    float we[8], pr[8];
    we[0] = w0.x; we[1] = w0.y; we[2] = w0.z; we[3] = w0.w;
    we[4] = w1.x; we[5] = w1.y; we[6] = w1.z; we[7] = w1.w;
#pragma unroll
    for (int j = 0; j < 8; j++) pr[j] = b2f((ushort)prv[j]);

    float acc[8] = {0.f, 0.f, 0.f, 0.f, 0.f, 0.f, 0.f, 0.f};
    int s0 = offs[r];
    int s1 = (r + 1 < n_right) ? offs[r + 1] : n_edges;
    int e = s0 + g;
    for (; e + 4 < s1; e += 8) {       // two edges per group in flight
        int2 ea = sle[e];
        int2 eb = sle[e + 4];
        short8 pa = *(const short8*)(Pl + (size_t)ea.x * EMB + m * 8);
        short8 pb = *(const short8*)(Pl + (size_t)eb.x * EMB + m * 8);
        float fa = __int_as_float(ea.y), fb = __int_as_float(eb.y);
#pragma unroll
        for (int j = 0; j < 8; j++) {
            acc[j] += fmaxf((b2f((ushort)pa[j]) + pr[j] + fa * we[j]) * scale, 0.f);
            acc[j] += fmaxf((b2f((ushort)pb[j]) + pr[j] + fb * we[j]) * scale, 0.f);
        }
    }
    if (e < s1) {                      // at most one leftover per group
        int2 ea = sle[e];
        short8 pa = *(const short8*)(Pl + (size_t)ea.x * EMB + m * 8);
        float fa = __int_as_float(ea.y);
#pragma unroll
        for (int j = 0; j < 8; j++)
            acc[j] += fmaxf((b2f((ushort)pa[j]) + pr[j] + fa * we[j]) * scale, 0.f);
    }
#pragma unroll
    for (int j = 0; j < 8; j++) {
        acc[j] += __shfl_xor(acc[j], 16);
        acc[j] += __shfl_xor(acc[j], 32);
    }
    if (g == 0) {
        short8 o;
#pragma unroll
        for (int j = 0; j < 8; j++) o[j] = f2b(acc[j]);
        *(short8*)(S + (size_t)r * EMB + m * 8) = o;
    }
}

// ---------------------------------------------------------------------------
// conv GEMM + output MLP with LDS-staged weights (unchanged from round 4).
__global__ __launch_bounds__(256) void k_out(const ushort* __restrict__ S,
                                             const float* __restrict__ right,
                                             const ushort* __restrict__ Wfb,
                                             const float* __restrict__ bf,
                                             const int* __restrict__ deg,
                                             const float* __restrict__ sc_post,
                                             const ushort* __restrict__ W1b,
                                             const float* __restrict__ b1,
                                             const ushort* __restrict__ W2b,
                                             const float* __restrict__ b2,
                                             float* __restrict__ out, int n) {
    __shared__ ushort Wlds[16384];       // 32KB staging buffer
    __shared__ ushort H[64][136];
    __shared__ float degs[64];
    int t = threadIdx.x, wave = t >> 6, lane = t & 63;
    int m = lane & 15, quad = lane >> 4;
    size_t row0 = (size_t)blockIdx.x * 64;
    int rl = wave * 16 + m;
    size_t xrow = row0 + rl;
    size_t xrowc = (xrow < (size_t)n) ? xrow : (size_t)(n - 1);
    bool ok = (xrow < (size_t)n);
    float sp = sc_post[0];

    // prologue: issue all per-wave global loads early
    short8 s4[4], ar[4];
    const ushort* sr = S + xrowc * EMB;
    const float* rr = right + xrowc * EMB;
#pragma unroll
    for (int ks = 0; ks < 4; ks++)
        s4[ks] = *(const short8*)(sr + ks * 32 + quad * 8);
    stage32k<8>(Wfb, Wlds, t);
#pragma unroll
    for (int ks = 0; ks < 4; ks++)
        ar[ks] = cvt8(rr + ks * 32 + quad * 8);
    if (t < 64) {
        size_t rr2 = row0 + t;
        degs[t] = (rr2 < (size_t)n) ? (float)deg[rr2] : 0.f;
    }
    __syncthreads();                      // Wf + degs ready
    float dd = degs[rl];

    // ---- phase 1: conv = (S @ Wf^T + deg*bf) * sp -> H ----
#pragma unroll
    for (int wt = 0; wt < 8; wt++) {
        floatx4 acc = {0.f, 0.f, 0.f, 0.f};
#pragma unroll
        for (int ks = 0; ks < 4; ks++) {
            short8 w = ldsW8(Wlds, ((wt * 16 + m) << 8) + (ks << 6) + (quad << 4));
            acc = MFMA(w, s4[ks], acc);
        }
        float4 bb = *(const float4*)(bf + wt * 16 + quad * 4);
        short4v o;
        o[0] = f2b((acc[0] + dd * bb.x) * sp);
        o[1] = f2b((acc[1] + dd * bb.y) * sp);
        o[2] = f2b((acc[2] + dd * bb.z) * sp);
        o[3] = f2b((acc[3] + dd * bb.w) * sp);
        *(short4v*)(&H[rl][wt * 16 + quad * 4]) = o;
    }
    // conv B-frags (wave-local H rows; lgkmcnt orders within the wave)
    short8 c4[4];
#pragma unroll
    for (int ks = 0; ks < 4; ks++)
        c4[ks] = *(const short8*)(&H[rl][ks * 32 + quad * 8]);
    __syncthreads();                      // all waves done reading Wf
    stage32k<9>(W1b, Wlds, t);            // W1 rows 0..63 (out cols 0..63)
    __syncthreads();

    // ---- phase 2a: hidden cols 0..63 ----
#pragma unroll
    for (int wt = 0; wt < 4; wt++) {
        floatx4 acc = {0.f, 0.f, 0.f, 0.f};
        int rb = wt * 16 + m;             // buffer-local W1 row
#pragma unroll
        for (int ks = 0; ks < 4; ks++) {
            short8 w = ldsW9(Wlds, (rb << 9) + (ks << 6) + (quad << 4));
            acc = MFMA(w, c4[ks], acc);
        }
#pragma unroll
        for (int ks = 0; ks < 4; ks++) {
            short8 w = ldsW9(Wlds, (rb << 9) + 256 + (ks << 6) + (quad << 4));
            acc = MFMA(w, ar[ks], acc);
        }
        float4 bb = *(const float4*)(b1 + wt * 16 + quad * 4);
        short4v o;
        o[0] = f2b(fmaxf(acc[0] + bb.x, 0.f));
        o[1] = f2b(fmaxf(acc[1] + bb.y, 0.f));
        o[2] = f2b(fmaxf(acc[2] + bb.z, 0.f));
        o[3] = f2b(fmaxf(acc[3] + bb.w, 0.f));
        *(short4v*)(&H[rl][wt * 16 + quad * 4]) = o;
    }
    __syncthreads();                      // done reading W1a
    stage32k<9>(W1b + 16384, Wlds, t);    // W1 rows 64..127
    __syncthreads();

    // ---- phase 2b: hidden cols 64..127 ----
#pragma unroll
    for (int wt = 4; wt < 8; wt++) {
        floatx4 acc = {0.f, 0.f, 0.f, 0.f};
        int rb = (wt - 4) * 16 + m;
#pragma unroll
        for (int ks = 0; ks < 4; ks++) {
            short8 w = ldsW9(Wlds, (rb << 9) + (ks << 6) + (quad << 4));
            acc = MFMA(w, c4[ks], acc);
        }
#pragma unroll
        for (int ks = 0; ks < 4; ks++) {
            short8 w = ldsW9(Wlds, (rb << 9) + 256 + (ks << 6) + (quad << 4));
            acc = MFMA(w, ar[ks], acc);
        }
        float4 bb = *(const float4*)(b1 + wt * 16 + quad * 4);
        short4v o;
        o[0] = f2b(fmaxf(acc[0] + bb.x, 0.f));
        o[1] = f2b(fmaxf(acc[1] + bb.y, 0.f));
        o[2] = f2b(fmaxf(acc[2] + bb.z, 0.f));
        o[3] = f2b(fmaxf(acc[3] + bb.w, 0.f));
        *(short4v*)(&H[rl][wt * 16 + quad * 4]) = o;
    }
    short8 h4[4];
#pragma unroll
    for (int ks = 0; ks < 4; ks++)
        h4[ks] = *(const short8*)(&H[rl][ks * 32 + quad * 8]);
    __syncthreads();                      // done reading W1b
    stage32k<8>(W2b, Wlds, t);
    __syncthreads();

    // ---- phase 3: out = hidden @ W2^T + b2 (coalesced float4 stores) ----
#pragma unroll
    for (int wt = 0; wt < 8; wt++) {
        floatx4 acc = {0.f, 0.f, 0.f, 0.f};
#pragma unroll
        for (int ks = 0; ks < 4; ks++) {
            short8 w = ldsW8(Wlds, ((wt * 16 + m) << 8) + (ks << 6) + (quad << 4));
            acc = MFMA(w, h4[ks], acc);
        }
        if (ok) {
            float4 bb = *(const float4*)(b2 + wt * 16 + quad * 4);
            float4 o;
            o.x = acc[0] + bb.x;
            o.y = acc[1] + bb.y;
            o.z = acc[2] + bb.z;
            o.w = acc[3] + bb.w;
            *(float4*)(out + xrow * EMB + wt * 16 + quad * 4) = o;
        }
    }
}

// ---------------------------------------------------------------------------
extern "C" void kernel_launch(void* const* d_in, const int* in_sizes, int n_in,
                              void* d_out, int out_size, void* d_ws, size_t ws_size,
                              hipStream_t stream) {
    const float* left   = (const float*)d_in[0];
    const int*   eidx   = (const int*)  d_in[1];
    const float* efeat  = (const float*)d_in[2];
    const float* right  = (const float*)d_in[3];
    const float* W_left = (const float*)d_in[5];
    const float* b_left = (const float*)d_in[6];
    const float* W_edge = (const float*)d_in[7];
    const float* W_right= (const float*)d_in[8];
    const float* sc_fin = (const float*)d_in[9];
    const float* W_fin  = (const float*)d_in[10];
    const float* b_fin  = (const float*)d_in[11];
    const float* sc_post= (const float*)d_in[12];
    const float* W_out1 = (const float*)d_in[13];
    const float* b_out1 = (const float*)d_in[14];
    const float* W_out2 = (const float*)d_in[15];
    const float* b_out2 = (const float*)d_in[16];

    int n_left  = in_sizes[0] / EMB;        // 100000
    int n_edges = in_sizes[2];              // 600000
    int n_right = in_sizes[3] / EMB;        // 100000

    ushort* us = (ushort*)d_ws;
    ushort* Wl_b = us;                       // packed bf16 weights
    ushort* Wr_b = us + 16384;
    ushort* Wf_b = us + 32768;
    ushort* W1_b = us + 49152;
    ushort* W2_b = us + 81920;
    ushort* Pl   = us + 98304;               // n_left*128
    ushort* Pr   = Pl + (size_t)n_left * EMB;
    ushort* S    = Pr + (size_t)n_right * EMB;
    int* cnt    = (int*)(S + (size_t)n_right * EMB);
    int* offs   = cnt + n_right;
    int* cursor = offs + n_right;
    int* bsum   = cursor + n_right;
    int2* sle   = (int2*)(bsum + 64);

    hipMemsetAsync(cnt, 0, (size_t)n_right * sizeof(int), stream);

    int eb = (n_edges + 255) / 256;          // 2344 (histogram + scatter)
    int nsb = (n_right + SCAN_CHUNK - 1) / SCAN_CHUNK;   // 25

    // weights->bf16 + degree histogram (independent, one launch)
    k_cvthist<<<384 + eb, 256, 0, stream>>>(W_left, W_right, W_fin, W_out1,
                                            W_out2, us, eidx, cnt, n_edges);

    // exclusive scan of degrees
    k_scan1<<<nsb, 1024, 0, stream>>>(cnt, offs, bsum, n_right);
    k_scan2<<<nsb, 1024, 0, stream>>>(bsum, offs, cursor, n_right);

    // scatter (blocks first) + gload_lds double-buffered projections
    k_permproj<<<eb + 2 * PB, 256, 0, stream>>>(eidx, efeat, cursor, sle,
                                                n_edges, left, right,
                                                Wl_b, Wr_b, b_left,
                                                Pl, Pr, n_left, eb);

    // segmented reduction -> S (one wave per right node, 4-wide gather)
    k_reduce<<<(n_right + 3) / 4, 256, 0, stream>>>(Pl, Pr, sle, W_edge, offs,
                                                    sc_fin, S, n_right, n_edges);

    // conv GEMM + output MLP (LDS-staged weights)
    k_out<<<(n_right + 63) / 64, 256, 0, stream>>>(S, right, Wf_b, b_fin,
                                                   cnt, sc_post, W1_b, b_out1,
                                                   W2_b, b_out2,
                                                   (float*)d_out, n_right);
}